// Round 9
// baseline (301.052 us; speedup 1.0000x reference)
//
#include <hip/hip_runtime.h>
#include <cstdint>
#include <cstddef>

typedef __bf16 bf16_t;
typedef __bf16 bf16x8 __attribute__((ext_vector_type(8)));
typedef __bf16 bf16x4 __attribute__((ext_vector_type(4)));
typedef _Float16 f16_t;
typedef _Float16 f16x4 __attribute__((ext_vector_type(4)));
typedef float f32x4 __attribute__((ext_vector_type(4)));

constexpr int BB = 2, SS = 2048, DD = 1024, HH = 16, HDIM = 64;
constexpr int BS = BB * SS;  // 4096
constexpr float LOG2E = 1.4426950408889634f;

// async global->LDS, 16B per lane; LDS dest is wave-uniform base + lane*16
__device__ __forceinline__ void glds16(const void* g, void* l) {
  __builtin_amdgcn_global_load_lds((const __attribute__((address_space(1))) void*)g,
                                   (__attribute__((address_space(3))) void*)l, 16, 0, 0);
}

// ---------------- fused input prep: convert_x | weight transposes | bias+mask ----------------
__global__ __launch_bounds__(256) void prep_fused(
    const float* __restrict__ x, const float* __restrict__ wq, const float* __restrict__ wk,
    const float* __restrict__ wv, const float* __restrict__ wo, const float* __restrict__ bias,
    const int* __restrict__ mask, bf16_t* __restrict__ xb, bf16_t* __restrict__ wqkv_t,
    bf16_t* __restrict__ wo_t, bf16_t* __restrict__ bmq) {
  __shared__ float tile[64][65];
  int bid = blockIdx.x;
  int t = threadIdx.x;
  if (bid < 4096) {
    int i = bid * 256 + t;
    float4 v = ((const float4*)x)[i];
    union { bf16_t h[4]; uint2 u; } o;
    o.h[0] = (bf16_t)v.x; o.h[1] = (bf16_t)v.y; o.h[2] = (bf16_t)v.z; o.h[3] = (bf16_t)v.w;
    ((uint2*)xb)[i] = o.u;
  } else if (bid < 5120) {
    int id = bid - 4096;
    int which = id >> 8, tr = (id >> 4) & 15, tc = id & 15;
    const float* src = (which == 0) ? wq : (which == 1) ? wk : (which == 2) ? wv : wo;
    bf16_t* dst = (which < 3) ? wqkv_t : wo_t;
    int noff = (which < 3) ? which * 1024 : 0;
#pragma unroll
    for (int p = 0; p < 4; ++p) {
      int e = (p * 256 + t) * 4;
      int r = e >> 6, c = e & 63;
      float4 v = *(const float4*)&src[(size_t)(tr * 64 + r) * 1024 + tc * 64 + c];
      tile[r][c] = v.x; tile[r][c + 1] = v.y; tile[r][c + 2] = v.z; tile[r][c + 3] = v.w;
    }
    __syncthreads();
#pragma unroll
    for (int p = 0; p < 4; ++p) {
      int e = (p * 256 + t) * 4;
      int r = e >> 6, c = e & 63;
      union { bf16_t h[4]; uint2 u; } o;
#pragma unroll
      for (int j = 0; j < 4; ++j) o.h[j] = (bf16_t)tile[c + j][r];
      *(uint2*)&dst[(size_t)(noff + tc * 64 + r) * 1024 + tr * 64 + c] = o.u;
    }
  } else {
    int i = (bid - 5120) * 256 + t;
    float4 b0 = ((const float4*)bias)[i * 2];
    float4 b1 = ((const float4*)bias)[i * 2 + 1];
    int4 m0 = ((const int4*)mask)[i * 2];
    int4 m1 = ((const int4*)mask)[i * 2 + 1];
    union { bf16_t h[8]; uint4 u; } o;
    o.h[0] = (bf16_t)(m0.x ? b0.x * LOG2E - 8.0f : -2.0e38f);
    o.h[1] = (bf16_t)(m0.y ? b0.y * LOG2E - 8.0f : -2.0e38f);
    o.h[2] = (bf16_t)(m0.z ? b0.z * LOG2E - 8.0f : -2.0e38f);
    o.h[3] = (bf16_t)(m0.w ? b0.w * LOG2E - 8.0f : -2.0e38f);
    o.h[4] = (bf16_t)(m1.x ? b1.x * LOG2E - 8.0f : -2.0e38f);
    o.h[5] = (bf16_t)(m1.y ? b1.y * LOG2E - 8.0f : -2.0e38f);
    o.h[6] = (bf16_t)(m1.z ? b1.z * LOG2E - 8.0f : -2.0e38f);
    o.h[7] = (bf16_t)(m1.w ? b1.w * LOG2E - 8.0f : -2.0e38f);
    ((uint4*)bmq)[i] = o.u;
  }
}

// ---------------- GEMM (m97 BK=64): C[M,N] = A[M,K] * Bt[N,K]^T ----------------
// MODE 0: fp32 out + bias (out projection)
// MODE 2: fused QKV epilogue -- LN(q,k)+relayout to [b,h,s,e] bf16; v + bias -> f16 row-major
template <int MODE>
__global__ __launch_bounds__(256) void gemm_bt(
    const bf16_t* __restrict__ A, const bf16_t* __restrict__ Bt, float* __restrict__ Cf,
    const float* __restrict__ bias, bf16_t* __restrict__ qbo, bf16_t* __restrict__ kbo,
    f16_t* __restrict__ cvo, const float* __restrict__ bq, const float* __restrict__ bk,
    const float* __restrict__ bv, const float* __restrict__ qs, const float* __restrict__ ks,
    int M, int N, int Kd) {
  __shared__ __align__(16) bf16_t As[128][64];
  __shared__ __align__(16) bf16_t Bs[128][64];
  int tid = threadIdx.x;
  int lane = tid & 63, w = tid >> 6;
  int lo = lane & 15, quad = lane >> 4;
  int wm = w >> 1, wn = w & 1;
  int m0 = blockIdx.y * 128, n0 = blockIdx.x * 128;
  int srow = lane >> 3;        // 0..7: row within an 8-row stripe
  int scol = (lane & 7) * 8;   // 16B chunk within the 128B row
  f32x4 acc[4][4] = {};
  for (int kk = 0; kk < Kd; kk += 64) {
#pragma unroll
    for (int t = 0; t < 4; ++t) {
      int rb = (w * 4 + t) * 8;  // wave-uniform stripe base row
      glds16(&A[(size_t)(m0 + rb + srow) * Kd + kk + scol], &As[rb][0]);
      glds16(&Bt[(size_t)(n0 + rb + srow) * Kd + kk + scol], &Bs[rb][0]);
    }
    asm volatile("s_waitcnt vmcnt(0)" ::: "memory");
    __syncthreads();
#pragma unroll
    for (int kc = 0; kc < 2; ++kc) {
      bf16x8 am[4], bn[4];
#pragma unroll
      for (int i = 0; i < 4; ++i)
        am[i] = *(const bf16x8*)&As[wm * 64 + i * 16 + lo][kc * 32 + quad * 8];
#pragma unroll
      for (int i = 0; i < 4; ++i)
        bn[i] = *(const bf16x8*)&Bs[wn * 64 + i * 16 + lo][kc * 32 + quad * 8];
#pragma unroll
      for (int mi = 0; mi < 4; ++mi)
#pragma unroll
        for (int ni = 0; ni < 4; ++ni)
          acc[mi][ni] = __builtin_amdgcn_mfma_f32_16x16x32_bf16(am[mi], bn[ni], acc[mi][ni], 0, 0, 0);
    }
    __syncthreads();
  }

  if (MODE == 0) {
#pragma unroll
    for (int mi = 0; mi < 4; ++mi)
#pragma unroll
      for (int ni = 0; ni < 4; ++ni)
#pragma unroll
        for (int r = 0; r < 4; ++r) {
          int row = m0 + wm * 64 + mi * 16 + quad * 4 + r;
          int col = n0 + wn * 64 + ni * 16 + lo;
          Cf[(size_t)row * N + col] = acc[mi][ni][r] + bias[col];
        }
  } else {
    // section: 0=q, 1=k, 2=v; each 128-col block = 2 heads, wave wn owns one head
    int sec = blockIdx.x >> 3;
    int hh = ((blockIdx.x & 7) << 1) + wn;
    const float* badd = (sec == 0) ? bq : (sec == 1) ? bk : bv;
    float bia[4], scv[4];
#pragma unroll
    for (int ni = 0; ni < 4; ++ni) bia[ni] = badd[hh * 64 + ni * 16 + lo];
    if (sec < 2) {
      const float* scp = (sec == 0) ? qs : ks;
#pragma unroll
      for (int ni = 0; ni < 4; ++ni) scv[ni] = scp[ni * 16 + lo];
    }
#pragma unroll
    for (int mi = 0; mi < 4; ++mi) {
#pragma unroll
      for (int r = 0; r < 4; ++r) {
        float x[4];
#pragma unroll
        for (int ni = 0; ni < 4; ++ni) x[ni] = acc[mi][ni][r] + bia[ni];
        int bs = m0 + wm * 64 + mi * 16 + quad * 4 + r;
        if (sec < 2) {
          float s1 = x[0] + x[1] + x[2] + x[3];
          float s2 = x[0] * x[0] + x[1] * x[1] + x[2] * x[2] + x[3] * x[3];
#pragma unroll
          for (int off = 8; off >= 1; off >>= 1) {
            s1 += __shfl_xor(s1, off, 64);
            s2 += __shfl_xor(s2, off, 64);
          }
          float mean = s1 * (1.0f / 64.0f);
          float var = s2 * (1.0f / 64.0f) - mean * mean;
          float inv = rsqrtf(fmaxf(var, 0.0f) + 1e-6f);
          float mul = inv * ((sec == 0) ? 0.125f * LOG2E : 1.0f);
          bf16_t* dst = ((sec == 0) ? qbo : kbo) +
                        ((size_t)(((bs >> 11) << 4) + hh) * 2048 + (bs & 2047)) * 64;
#pragma unroll
          for (int ni = 0; ni < 4; ++ni)
            dst[ni * 16 + lo] = (bf16_t)((x[ni] - mean) * mul * scv[ni]);
        } else {
          f16_t* dst = cvo + (size_t)bs * 1024 + hh * 64;
#pragma unroll
          for (int ni = 0; ni < 4; ++ni) dst[ni * 16 + lo] = (f16_t)x[ni];
        }
      }
    }
  }
}

// ---------------- V transpose: cv [b*S][h*64+e] f16 -> vt [b,h][e][s] f16 ----------------
__global__ __launch_bounds__(256) void vt_small(const f16_t* __restrict__ cv,
                                                f16_t* __restrict__ vt) {
  __shared__ f16_t tile[64][72];
  int st = blockIdx.x, h = blockIdx.y, b = blockIdx.z;
  int t = threadIdx.x;
#pragma unroll
  for (int p = 0; p < 2; ++p) {
    int e = (p * 256 + t) * 8;
    int r = e >> 6, c = e & 63;  // r = s-local, c = e-local
    *(uint4*)&tile[r][c] = *(const uint4*)&cv[(size_t)(b * SS + st * 64 + r) * 1024 + h * 64 + c];
  }
  __syncthreads();
#pragma unroll
  for (int p = 0; p < 2; ++p) {
    int e = (p * 256 + t) * 8;
    int r = e >> 6, c = e & 63;  // r = e-row, c = s-col
    union { f16_t h[8]; uint4 u; } o;
#pragma unroll
    for (int j = 0; j < 8; ++j) o.h[j] = tile[c + j][r];
    *(uint4*)&vt[(size_t)((b * HH + h) * HDIM + r) * SS + st * 64 + c] = o.u;
  }
}

// ---------------- flash attention (R6 best): 256 thr, 4 waves x 32 q, register-resident P ----------------
__global__ __launch_bounds__(256) void attn_kernel(const bf16_t* __restrict__ qb,
                                                   const bf16_t* __restrict__ kb,
                                                   const f16_t* __restrict__ vt,
                                                   const bf16_t* __restrict__ bmq,
                                                   bf16_t* __restrict__ xout) {
  __shared__ __align__(16) bf16_t Ks[64][72];   // [k][e]
  __shared__ __align__(16) f16_t Vs[64][72];    // [e][k]
  __shared__ __align__(16) bf16_t Bm[128][72];  // [q][k]
  int tid = threadIdx.x;
  int lane = tid & 63, w = tid >> 6;
  int lo = lane & 15, quad = lane >> 4;
  int qt = blockIdx.x, h = blockIdx.y, b = blockIdx.z;
  size_t headoff = (size_t)(b * HH + h) * SS * HDIM;
  int q0b = qt * 128;
  int q0 = q0b + w * 32;
  const bf16_t* kbase = kb + headoff;
  const f16_t* vbase = vt + headoff;
  const bf16_t* bmbase = bmq + (size_t)b * SS * SS;

  bf16x8 bqf[2][2];
#pragma unroll
  for (int qg = 0; qg < 2; ++qg)
#pragma unroll
    for (int ec = 0; ec < 2; ++ec)
      bqf[qg][ec] =
          *(const bf16x8*)&qb[headoff + (size_t)(q0 + qg * 16 + lo) * HDIM + ec * 32 + quad * 8];

  f16x4 ones;
#pragma unroll
  for (int j = 0; j < 4; ++j) ones[j] = (f16_t)1.0f;

  f32x4 ot[2][4] = {};
  f32x4 lacc[2] = {};

  for (int kt = 0; kt < SS / 64; ++kt) {
    int k0 = kt * 64;
#pragma unroll
    for (int p = 0; p < 2; ++p) {
      int idx = (p * 256 + tid) * 8;
      int r = idx >> 6, c = idx & 63;
      *(uint4*)&Ks[r][c] = *(const uint4*)&kbase[(size_t)(k0 + r) * HDIM + c];
      *(uint4*)&Vs[r][c] = *(const uint4*)&vbase[(size_t)r * SS + k0 + c];
    }
#pragma unroll
    for (int p = 0; p < 4; ++p) {
      int idx = (p * 256 + tid) * 8;
      int r = idx >> 6, c = idx & 63;
      *(uint4*)&Bm[r][c] = *(const uint4*)&bmbase[(size_t)(q0b + r) * SS + k0 + c];
    }
    __syncthreads();

    bf16x8 ka[4][2];
#pragma unroll
    for (int mb = 0; mb < 4; ++mb)
#pragma unroll
      for (int ec = 0; ec < 2; ++ec)
        ka[mb][ec] = *(const bf16x8*)&Ks[mb * 16 + lo][ec * 32 + quad * 8];

    f16x4 pf[2][4];
#pragma unroll
    for (int qg = 0; qg < 2; ++qg) {
#pragma unroll
      for (int mb = 0; mb < 4; ++mb) {
        bf16x4 bm4 = *(const bf16x4*)&Bm[w * 32 + qg * 16 + lo][mb * 16 + quad * 4];
        f32x4 s;
#pragma unroll
        for (int r = 0; r < 4; ++r) s[r] = (float)bm4[r];
        s = __builtin_amdgcn_mfma_f32_16x16x32_bf16(ka[mb][0], bqf[qg][0], s, 0, 0, 0);
        s = __builtin_amdgcn_mfma_f32_16x16x32_bf16(ka[mb][1], bqf[qg][1], s, 0, 0, 0);
#pragma unroll
        for (int r = 0; r < 4; ++r) pf[qg][mb][r] = (f16_t)__builtin_amdgcn_exp2f(s[r]);
      }
    }

#pragma unroll
    for (int mb = 0; mb < 4; ++mb) {
#pragma unroll
      for (int eb = 0; eb < 4; ++eb) {
        f16x4 va = *(const f16x4*)&Vs[eb * 16 + lo][mb * 16 + quad * 4];
#pragma unroll
        for (int qg = 0; qg < 2; ++qg)
          ot[qg][eb] = __builtin_amdgcn_mfma_f32_16x16x16f16(va, pf[qg][mb], ot[qg][eb], 0, 0, 0);
      }
#pragma unroll
      for (int qg = 0; qg < 2; ++qg)
        lacc[qg] = __builtin_amdgcn_mfma_f32_16x16x16f16(ones, pf[qg][mb], lacc[qg], 0, 0, 0);
    }
    __syncthreads();
  }

#pragma unroll
  for (int qg = 0; qg < 2; ++qg) {
    float rl = 1.0f / lacc[qg][0];
    int q = q0 + qg * 16 + lo;
#pragma unroll
    for (int eb = 0; eb < 4; ++eb) {
      union { bf16_t h4[4]; uint2 u; } o;
#pragma unroll
      for (int r = 0; r < 4; ++r) o.h4[r] = (bf16_t)(ot[qg][eb][r] * rl);
      *(uint2*)&xout[(size_t)(b * SS + q) * DD + h * 64 + eb * 16 + quad * 4] = o.u;
    }
  }
}

extern "C" void kernel_launch(void* const* d_in, const int* in_sizes, int n_in, void* d_out,
                              int out_size, void* d_ws, size_t ws_size, hipStream_t stream) {
  const float* inputs_q = (const float*)d_in[0];
  const float* bias = (const float*)d_in[1];
  const int* mask = (const int*)d_in[2];
  const float* wq = (const float*)d_in[3];
  const float* bq = (const float*)d_in[4];
  const float* wk = (const float*)d_in[5];
  const float* bk = (const float*)d_in[6];
  const float* wv = (const float*)d_in[7];
  const float* bv = (const float*)d_in[8];
  const float* q_scale = (const float*)d_in[9];
  const float* k_scale = (const float*)d_in[10];
  const float* wo = (const float*)d_in[11];
  const float* bo = (const float*)d_in[12];
  float* out = (float*)d_out;

  // ws packing (57 MB; overlaps only dead/live pairs):
  //   wo_t   0-2    (live to end)
  //   bmq    2-19   (prep -> attn)
  //   qb2    19-27  (gemm_qkv -> attn)
  //   kb2    27-35  (gemm_qkv -> attn)
  //   cv     35-43  (gemm_qkv -> vt)      xattn 35-43 (overlap; attn -> gemm_out)
  //   xb     43-51  (prep -> gemm_qkv)    vtb   43-51 (overlap; vt -> attn)
  //   wqkv_t 51-57  (prep -> gemm_qkv)
  char* ws = (char*)d_ws;
  bf16_t* wo_t   = (bf16_t*)(ws);
  bf16_t* bmq    = (bf16_t*)(ws + ((size_t)2 << 20));
  bf16_t* qb2    = (bf16_t*)(ws + ((size_t)19 << 20));
  bf16_t* kb2    = (bf16_t*)(ws + ((size_t)27 << 20));
  f16_t*  cv     = (f16_t*)(ws + ((size_t)35 << 20));
  bf16_t* xattn  = (bf16_t*)(ws + ((size_t)35 << 20));
  bf16_t* xb     = (bf16_t*)(ws + ((size_t)43 << 20));
  f16_t*  vtb    = (f16_t*)(ws + ((size_t)43 << 20));
  bf16_t* wqkv_t = (bf16_t*)(ws + ((size_t)51 << 20));

  prep_fused<<<9216, 256, 0, stream>>>(inputs_q, wq, wk, wv, wo, bias, mask, xb, wqkv_t, wo_t, bmq);
  gemm_bt<2><<<dim3(24, 32), 256, 0, stream>>>(xb, wqkv_t, nullptr, nullptr, qb2, kb2, cv, bq, bk,
                                               bv, q_scale, k_scale, BS, 3072, DD);
  vt_small<<<dim3(32, 16, 2), 256, 0, stream>>>(cv, vtb);
  attn_kernel<<<dim3(SS / 128, HH, BB), 256, 0, stream>>>(qb2, kb2, vtb, bmq, xattn);
  gemm_bt<0><<<dim3(8, 32), 256, 0, stream>>>(xattn, wo_t, out, bo, nullptr, nullptr, nullptr,
                                              nullptr, nullptr, nullptr, nullptr, nullptr, BS,
                                              1024, DD);
}